// Round 1
// baseline (450.675 us; speedup 1.0000x reference)
//
#include <hip/hip_runtime.h>
#include <hip/hip_bf16.h>

// S4D layer, fp32 baseline.
// Pipeline: prep (A_bar, power table, permuted B_w/C_w) -> GEMM1 (Bu = u @ B_w^T)
//  -> chunked scan (local, carry, fixup) -> fused GEMM2 (y = u @ D_w^T + H @ C_w^T).
// Complex data stored interleaved: Bu[m][2n]=re, Bu[m][2n+1]=im (B_w rows permuted).

#define D_MODEL 512
#define NSTATE  64
#define N2      128      // 2*NSTATE
#define BATCH   8
#define SEQ     4096
#define MTOT    (BATCH*SEQ)   // 32768
#define LC      16            // scan chunk length
#define NC      (SEQ/LC)      // 256 chunks per sequence

// ---- workspace offsets (floats) ----
#define OFF_ABAR   0                      // 128
#define OFF_POWTAB 128                    // LC*64*2 = 2048
#define OFF_BWP    2176                   // 128*512 = 65536
#define OFF_CWP    67712                  // 512*128 = 65536
#define OFF_BU     133248                 // 32768*128
#define OFF_H      4327552                // 32768*128
#define OFF_E      8521856                // 8*256*64*2
#define OFF_P      8784000                // 8*256*64*2
// total 9046144 floats = 36.2 MB

// ---------------------------------------------------------------------------
// prep: A_bar (bilinear discretization), power table a^(i+1), permuted weights
// ---------------------------------------------------------------------------
__global__ __launch_bounds__(256) void prep_kernel(
    const float* __restrict__ lar, const float* __restrict__ lai,
    const float* __restrict__ Bw,  const float* __restrict__ Cw,
    float* __restrict__ abar, float* __restrict__ powtab,
    float* __restrict__ Bwp,  float* __restrict__ Cwp)
{
    int tid = blockIdx.x * blockDim.x + threadIdx.x;
    if (blockIdx.x == 0 && threadIdx.x < 64) {
        int n = threadIdx.x;
        float ar = -expf(lar[n]);
        float ai = lai[n];
        const float h = 0.5f;  // 0.5*DT, DT=1
        float nr = 1.f + h * ar, ni = h * ai;
        float dr = 1.f - h * ar, di = -h * ai;
        float den = dr * dr + di * di;
        float Ar = (nr * dr + ni * di) / den;
        float Ai = (ni * dr - nr * di) / den;
        abar[2 * n] = Ar; abar[2 * n + 1] = Ai;
        // powtab[i][n] = a^(i+1), layout [LC][64] of float2
        float pr = Ar, pi = Ai;
        for (int i = 0; i < LC; ++i) {
            powtab[(i * 64 + n) * 2]     = pr;
            powtab[(i * 64 + n) * 2 + 1] = pi;
            float npr = pr * Ar - pi * Ai;
            float npi = pr * Ai + pi * Ar;
            pr = npr; pi = npi;
        }
    }
    // Bwp[np][k] = Bw[src(np)][k]  with src interleaving (re,im) pairs
    int total = N2 * D_MODEL;
    for (int idx = tid; idx < total; idx += gridDim.x * blockDim.x) {
        int np = idx / D_MODEL, k = idx % D_MODEL;
        int src = (np & 1) ? (64 + (np >> 1)) : (np >> 1);
        Bwp[idx] = Bw[src * D_MODEL + k];
    }
    // Cwp[d][np] = Cw[d][src(np)]
    for (int idx = tid; idx < total; idx += gridDim.x * blockDim.x) {
        int d = idx / N2, np = idx % N2;
        int src = (np & 1) ? (64 + (np >> 1)) : (np >> 1);
        Cwp[idx] = Cw[d * N2 + src];
    }
}

// ---------------------------------------------------------------------------
// Tiled fp32 GEMM core: C[m][n] += sum_k A[m][k]*B[n][k]   (B row-major N x K)
// BM=64, BN=128, BK=32, 256 threads, each thread 4x8 outputs.
// ---------------------------------------------------------------------------
#define BKg  32
#define LDAS 68    // 64 + 4 pad (keeps float4 alignment, breaks bank stride)
#define LDBS 132   // 128 + 4 pad

__device__ __forceinline__ void gemm_tile_loop(
    const float* __restrict__ A, int lda,
    const float* __restrict__ B, int ldb,   // pre-offset to its n0 row
    int K, int m0,
    float acc[4][8], float* As, float* Bs,
    int tid, int ty, int tx)
{
    int r  = tid >> 3;          // 0..31
    int kq = (tid & 7) << 2;    // 0,4,..,28
    for (int k0 = 0; k0 < K; k0 += BKg) {
        __syncthreads();  // previous compute done before overwriting LDS
#pragma unroll
        for (int rep = 0; rep < 2; ++rep) {   // A tile: 64 rows x 32 k
            int rr = r + rep * 32;
            float4 v = *(const float4*)&A[(m0 + rr) * lda + k0 + kq];
            As[(kq + 0) * LDAS + rr] = v.x;
            As[(kq + 1) * LDAS + rr] = v.y;
            As[(kq + 2) * LDAS + rr] = v.z;
            As[(kq + 3) * LDAS + rr] = v.w;
        }
#pragma unroll
        for (int rep = 0; rep < 4; ++rep) {   // B tile: 128 rows x 32 k
            int rr = r + rep * 32;
            float4 v = *(const float4*)&B[rr * ldb + k0 + kq];
            Bs[(kq + 0) * LDBS + rr] = v.x;
            Bs[(kq + 1) * LDBS + rr] = v.y;
            Bs[(kq + 2) * LDBS + rr] = v.z;
            Bs[(kq + 3) * LDBS + rr] = v.w;
        }
        __syncthreads();
#pragma unroll
        for (int kk = 0; kk < BKg; ++kk) {
            float4 a0 = *(const float4*)&As[kk * LDAS + ty * 4];
            float4 b0 = *(const float4*)&Bs[kk * LDBS + tx * 8];
            float4 b1 = *(const float4*)&Bs[kk * LDBS + tx * 8 + 4];
            float av[4] = {a0.x, a0.y, a0.z, a0.w};
            float bv[8] = {b0.x, b0.y, b0.z, b0.w, b1.x, b1.y, b1.z, b1.w};
#pragma unroll
            for (int i = 0; i < 4; ++i)
#pragma unroll
                for (int j = 0; j < 8; ++j)
                    acc[i][j] = fmaf(av[i], bv[j], acc[i][j]);
        }
    }
}

// GEMM1: Bu[32768][128] = u[32768][512] @ Bwp[128][512]^T
__global__ __launch_bounds__(256) void gemm1_kernel(
    const float* __restrict__ u, const float* __restrict__ Bwp,
    float* __restrict__ Bu)
{
    __shared__ __align__(16) float As[BKg * LDAS];
    __shared__ __align__(16) float Bs[BKg * LDBS];
    int tid = threadIdx.x;
    int ty = tid >> 4, tx = tid & 15;
    int m0 = blockIdx.x * 64;
    float acc[4][8] = {};
    gemm_tile_loop(u, D_MODEL, Bwp, D_MODEL, D_MODEL, m0, acc, As, Bs, tid, ty, tx);
#pragma unroll
    for (int i = 0; i < 4; ++i) {
        int row = m0 + ty * 4 + i;
        float4 lo = make_float4(acc[i][0], acc[i][1], acc[i][2], acc[i][3]);
        float4 hi = make_float4(acc[i][4], acc[i][5], acc[i][6], acc[i][7]);
        *(float4*)&Bu[row * N2 + tx * 8]     = lo;
        *(float4*)&Bu[row * N2 + tx * 8 + 4] = hi;
    }
}

// GEMM2 fused: y[m][d] = sum_k u[m][k]*Dw[d][k] + sum_k H[m][k]*Cwp[d][k]
__global__ __launch_bounds__(256) void gemm2_kernel(
    const float* __restrict__ u, const float* __restrict__ Dw,
    const float* __restrict__ H, const float* __restrict__ Cwp,
    float* __restrict__ y)
{
    __shared__ __align__(16) float As[BKg * LDAS];
    __shared__ __align__(16) float Bs[BKg * LDBS];
    int tid = threadIdx.x;
    int ty = tid >> 4, tx = tid & 15;
    int m0 = blockIdx.x * 64;
    int n0 = blockIdx.y * 128;
    float acc[4][8] = {};
    gemm_tile_loop(u, D_MODEL, Dw + n0 * D_MODEL, D_MODEL, D_MODEL, m0, acc, As, Bs, tid, ty, tx);
    gemm_tile_loop(H, N2,      Cwp + n0 * N2,     N2,      N2,      m0, acc, As, Bs, tid, ty, tx);
#pragma unroll
    for (int i = 0; i < 4; ++i) {
        int row = m0 + ty * 4 + i;
        float4 lo = make_float4(acc[i][0], acc[i][1], acc[i][2], acc[i][3]);
        float4 hi = make_float4(acc[i][4], acc[i][5], acc[i][6], acc[i][7]);
        *(float4*)&y[row * D_MODEL + n0 + tx * 8]     = lo;
        *(float4*)&y[row * D_MODEL + n0 + tx * 8 + 4] = hi;
    }
}

// ---------------------------------------------------------------------------
// Scan phase A: local chunk scans (h0 = 0), write local H and chunk-end E.
// block = (b, chunk), 64 threads = 64 complex chains. Coalesced float2 I/O.
// ---------------------------------------------------------------------------
__global__ __launch_bounds__(64) void scan_local_kernel(
    const float* __restrict__ Bu, const float* __restrict__ abar,
    float* __restrict__ H, float* __restrict__ E)
{
    int n = threadIdx.x;
    int bx = blockIdx.x;
    int b = bx >> 8, c = bx & (NC - 1);
    float Ar = abar[2 * n], Ai = abar[2 * n + 1];
    float hr = 0.f, hi = 0.f;
    int base = (b * SEQ + c * LC) * N2 + 2 * n;
#pragma unroll
    for (int i = 0; i < LC; ++i) {
        float2 x = *(const float2*)&Bu[base + i * N2];
        float nhr = fmaf(Ar, hr, fmaf(-Ai, hi, x.x));
        float nhi = fmaf(Ar, hi, fmaf(Ai, hr, x.y));
        hr = nhr; hi = nhi;
        *(float2*)&H[base + i * N2] = make_float2(hr, hi);
    }
    *(float2*)&E[((b * NC + c) * 64 + n) * 2] = make_float2(hr, hi);
}

// Scan phase B: sequential prefix over chunk carries. P[c] = carry INTO chunk c.
__global__ __launch_bounds__(64) void scan_carry_kernel(
    const float* __restrict__ E, const float* __restrict__ powtab,
    float* __restrict__ P)
{
    int n = threadIdx.x;
    int b = blockIdx.x;
    float aLr = powtab[((LC - 1) * 64 + n) * 2];      // a^LC
    float aLi = powtab[((LC - 1) * 64 + n) * 2 + 1];
    float pr = 0.f, pi = 0.f;
    for (int c = 0; c < NC; ++c) {
        int idx = ((b * NC + c) * 64 + n) * 2;
        P[idx] = pr; P[idx + 1] = pi;
        float2 e = *(const float2*)&E[idx];
        float npr = fmaf(aLr, pr, fmaf(-aLi, pi, e.x));
        float npi = fmaf(aLr, pi, fmaf(aLi, pr, e.y));
        pr = npr; pi = npi;
    }
}

// Scan phase C: H[t] += a^(i+1) * P[chunk]  (exact cross-chunk fixup)
__global__ __launch_bounds__(64) void scan_fix_kernel(
    float* __restrict__ H, const float* __restrict__ P,
    const float* __restrict__ powtab)
{
    int n = threadIdx.x;
    int bx = blockIdx.x;
    int b = bx >> 8, c = bx & (NC - 1);
    if (c == 0) return;  // zero carry into first chunk
    float2 p = *(const float2*)&P[((b * NC + c) * 64 + n) * 2];
    int base = (b * SEQ + c * LC) * N2 + 2 * n;
#pragma unroll
    for (int i = 0; i < LC; ++i) {
        float2 w = *(const float2*)&powtab[(i * 64 + n) * 2];
        float cr = w.x * p.x - w.y * p.y;
        float ci = fmaf(w.x, p.y, w.y * p.x);
        float2 hcur = *(const float2*)&H[base + i * N2];
        hcur.x += cr; hcur.y += ci;
        *(float2*)&H[base + i * N2] = hcur;
    }
}

// ---------------------------------------------------------------------------
extern "C" void kernel_launch(void* const* d_in, const int* in_sizes, int n_in,
                              void* d_out, int out_size, void* d_ws, size_t ws_size,
                              hipStream_t stream)
{
    const float* u   = (const float*)d_in[0];
    const float* lar = (const float*)d_in[1];
    const float* lai = (const float*)d_in[2];
    const float* Bw  = (const float*)d_in[3];
    const float* Cw  = (const float*)d_in[4];
    const float* Dw  = (const float*)d_in[5];
    float* y  = (float*)d_out;
    float* ws = (float*)d_ws;

    float* abar   = ws + OFF_ABAR;
    float* powtab = ws + OFF_POWTAB;
    float* Bwp    = ws + OFF_BWP;
    float* Cwp    = ws + OFF_CWP;
    float* Bu     = ws + OFF_BU;
    float* H      = ws + OFF_H;
    float* E      = ws + OFF_E;
    float* P      = ws + OFF_P;

    hipLaunchKernelGGL(prep_kernel, dim3(128), dim3(256), 0, stream,
                       lar, lai, Bw, Cw, abar, powtab, Bwp, Cwp);
    hipLaunchKernelGGL(gemm1_kernel, dim3(MTOT / 64), dim3(256), 0, stream,
                       u, Bwp, Bu);
    hipLaunchKernelGGL(scan_local_kernel, dim3(BATCH * NC), dim3(64), 0, stream,
                       Bu, abar, H, E);
    hipLaunchKernelGGL(scan_carry_kernel, dim3(BATCH), dim3(64), 0, stream,
                       E, powtab, P);
    hipLaunchKernelGGL(scan_fix_kernel, dim3(BATCH * NC), dim3(64), 0, stream,
                       H, P, powtab);
    hipLaunchKernelGGL(gemm2_kernel, dim3(MTOT / 64, D_MODEL / 128), dim3(256), 0, stream,
                       u, Dw, H, Cwp, y);
}

// Round 3
// 202.807 us; speedup vs baseline: 2.2222x; 2.2222x over previous
//
#include <hip/hip_runtime.h>
#include <hip/hip_bf16.h>

// S4D layer, bf16-MFMA version.
// prep (A_bar, powers, permuted bf16 weights) -> MFMA GEMM1 (Bu = u @ Bwp^T, f32 out)
//  -> in-place chunked scan on Bu (local / carry / fixup, all f32)
//  -> MFMA GEMM2 (y = [u | H] @ [Dw | Cwp]^T), A staged f32->bf16 in registers,
//     B staged bf16 via global_load_lds(16) with pre-swizzled source (T2 swizzle).

#define D_MODEL 512
#define NSTATE  64
#define N2      128
#define BATCH   8
#define SEQ     4096
#define MTOT    (BATCH*SEQ)    // 32768
#define LC      16
#define NC      (SEQ/LC)       // 256

// ---- workspace byte offsets ----
#define OFFB_ABAR   0u            // 512 B
#define OFFB_POWTAB 512u          // 8192 B
#define OFFB_BWPB   16384u        // 128*512*2  = 131072
#define OFFB_W2B    147456u       // 512*640*2  = 655360
#define OFFB_BU     1048576u      // 32768*128*4 = 16 MB (Bu, then H in place)
#define OFFB_E      17825792u     // 1 MB
#define OFFB_P      18874368u     // 1 MB  -> total ~20 MB

typedef __bf16  bf16x8  __attribute__((ext_vector_type(8)));
typedef float   f32x4   __attribute__((ext_vector_type(4)));
typedef unsigned short ushort8 __attribute__((ext_vector_type(8)));

__device__ __forceinline__ unsigned short f2bf(float f) {
    union { float f; unsigned int u; } v; v.f = f;
    unsigned int r = v.u + 0x7fffu + ((v.u >> 16) & 1u);   // RNE
    return (unsigned short)(r >> 16);
}

__device__ __forceinline__ void gload_lds16(const void* g, void* l) {
    __builtin_amdgcn_global_load_lds(
        (const __attribute__((address_space(1))) void*)g,
        (__attribute__((address_space(3))) void*)l, 16, 0, 0);
}

// ---------------------------------------------------------------------------
// prep: A_bar, power table, permuted bf16 weights Bwpb[128][512], W2b[512][640]
// ---------------------------------------------------------------------------
__global__ __launch_bounds__(256) void prep_kernel(
    const float* __restrict__ lar, const float* __restrict__ lai,
    const float* __restrict__ Bw,  const float* __restrict__ Cw,
    const float* __restrict__ Dw,
    float* __restrict__ abar, float* __restrict__ powtab,
    unsigned short* __restrict__ Bwpb, unsigned short* __restrict__ W2b)
{
    int tid = blockIdx.x * blockDim.x + threadIdx.x;
    if (blockIdx.x == 0 && threadIdx.x < 64) {
        int n = threadIdx.x;
        float ar = -expf(lar[n]);
        float ai = lai[n];
        const float h = 0.5f;
        float nr = 1.f + h * ar, ni = h * ai;
        float dr = 1.f - h * ar, di = -h * ai;
        float den = dr * dr + di * di;
        float Ar = (nr * dr + ni * di) / den;
        float Ai = (ni * dr - nr * di) / den;
        abar[2 * n] = Ar; abar[2 * n + 1] = Ai;
        float pr = Ar, pi = Ai;
        for (int i = 0; i < LC; ++i) {
            powtab[(i * 64 + n) * 2]     = pr;
            powtab[(i * 64 + n) * 2 + 1] = pi;
            float npr = pr * Ar - pi * Ai;
            float npi = pr * Ai + pi * Ar;
            pr = npr; pi = npi;
        }
    }
    int stride = gridDim.x * blockDim.x;
    // Bwpb[np][k] = bf16(Bw[src(np)][k])
    for (int idx = tid; idx < N2 * D_MODEL; idx += stride) {
        int np = idx / D_MODEL, k = idx % D_MODEL;
        int src = (np & 1) ? (64 + (np >> 1)) : (np >> 1);
        Bwpb[idx] = f2bf(Bw[src * D_MODEL + k]);
    }
    // W2b[d][k] = bf16( k<512 ? Dw[d][k] : Cw[d][src(k-512)] )
    for (int idx = tid; idx < D_MODEL * 640; idx += stride) {
        int d = idx / 640, k = idx % 640;
        float v;
        if (k < D_MODEL) v = Dw[d * D_MODEL + k];
        else {
            int np = k - D_MODEL;
            int src = (np & 1) ? (64 + (np >> 1)) : (np >> 1);
            v = Cw[d * N2 + src];
        }
        W2b[idx] = f2bf(v);
    }
}

// ---------------------------------------------------------------------------
// bf16 MFMA GEMM: C[m][n] = sum_k A[m][k] * W[n][k]
// A: f32, two K-segments (A1 K1 cols, then A2 K2 cols), converted while staging.
// W: bf16 row-major [N][ldb], k index runs over the concatenated range.
// Tile 128x128, BK=64, 256 threads (4 waves, 2x2 of 64x64), T2 XOR swizzle.
// ---------------------------------------------------------------------------
__global__ __launch_bounds__(256) void gemm_bf16_kernel(
    const float* __restrict__ A1, int lda1, int K1,
    const float* __restrict__ A2, int lda2, int K2,
    const unsigned short* __restrict__ W, int ldb,
    float* __restrict__ C, int ldc)
{
    __shared__ __align__(16) unsigned short As[128 * 64];
    __shared__ __align__(16) unsigned short Bs[128 * 64];
    const int tid  = threadIdx.x;
    const int lane = tid & 63;
    const int w    = tid >> 6;
    const int wm   = (w >> 1) * 64;
    const int wn   = (w & 1) * 64;
    const int m0   = blockIdx.x * 128;
    const int n0   = blockIdx.y * 128;

    f32x4 acc[4][4];
#pragma unroll
    for (int i = 0; i < 4; ++i)
#pragma unroll
        for (int j = 0; j < 4; ++j)
            acc[i][j] = (f32x4){0.f, 0.f, 0.f, 0.f};

    const int Ktot = K1 + K2;
    const int tr = tid >> 3;      // 0..31 row-within-quarter
    const int tc = tid & 7;       // 0..7  16B chunk

    for (int k0 = 0; k0 < Ktot; k0 += 64) {
        __syncthreads();   // previous compute done before LDS overwrite
        // ---- B tile via global_load_lds, pre-swizzled source ----
#pragma unroll
        for (int q = 0; q < 4; ++q) {
            int r = q * 32 + tr;
            int cs = tc ^ (r & 7);                       // source chunk
            gload_lds16(W + (size_t)(n0 + r) * ldb + k0 + cs * 8,
                        (char*)Bs + (q * 256 + tid) * 16);
        }
        // ---- A tile: f32 load + convert + swizzled ds_write ----
        const float* Ab; int lda_; int kk0;
        if (k0 < K1) { Ab = A1; lda_ = lda1; kk0 = k0; }
        else         { Ab = A2; lda_ = lda2; kk0 = k0 - K1; }
#pragma unroll
        for (int q = 0; q < 4; ++q) {
            int r = q * 32 + tr;
            const float* src = Ab + (size_t)(m0 + r) * lda_ + kk0 + tc * 8;
            float4 v0 = *(const float4*)src;
            float4 v1 = *(const float4*)(src + 4);
            ushort8 p;
            p[0] = f2bf(v0.x); p[1] = f2bf(v0.y); p[2] = f2bf(v0.z); p[3] = f2bf(v0.w);
            p[4] = f2bf(v1.x); p[5] = f2bf(v1.y); p[6] = f2bf(v1.z); p[7] = f2bf(v1.w);
            int cd = tc ^ (r & 7);                       // swizzled dest chunk
            *(ushort8*)((char*)As + r * 128 + cd * 16) = p;
        }
        __syncthreads();   // drains vmcnt (global_load_lds) + lgkmcnt (ds_write)

        // ---- compute: 2 k-substeps x 16 MFMA ----
#pragma unroll
        for (int kk = 0; kk < 2; ++kk) {
            bf16x8 a[4], b[4];
#pragma unroll
            for (int i = 0; i < 4; ++i) {
                int row = wm + i * 16 + (lane & 15);
                int kb  = kk * 64 + ((lane >> 4) << 4);
                a[i] = *(const bf16x8*)((const char*)As + row * 128 + (kb ^ ((row & 7) << 4)));
            }
#pragma unroll
            for (int j = 0; j < 4; ++j) {
                int row = wn + j * 16 + (lane & 15);
                int kb  = kk * 64 + ((lane >> 4) << 4);
                b[j] = *(const bf16x8*)((const char*)Bs + row * 128 + (kb ^ ((row & 7) << 4)));
            }
#pragma unroll
            for (int i = 0; i < 4; ++i)
#pragma unroll
                for (int j = 0; j < 4; ++j)
                    acc[i][j] = __builtin_amdgcn_mfma_f32_16x16x32_bf16(a[i], b[j], acc[i][j], 0, 0, 0);
        }
    }

    // ---- C write: col = lane&15, row = (lane>>4)*4 + r ----
#pragma unroll
    for (int i = 0; i < 4; ++i)
#pragma unroll
        for (int j = 0; j < 4; ++j) {
            int col = n0 + wn + j * 16 + (lane & 15);
#pragma unroll
            for (int r = 0; r < 4; ++r) {
                int row = m0 + wm + i * 16 + ((lane >> 4) << 2) + r;
                C[(size_t)row * ldc + col] = acc[i][j][r];
            }
        }
}

// ---------------------------------------------------------------------------
// Scan phase A: local chunk scans in place (Bu -> local H), chunk-end E.
// ---------------------------------------------------------------------------
__global__ __launch_bounds__(64) void scan_local_kernel(
    float* Bu, const float* __restrict__ abar, float* __restrict__ E)
{
    int n = threadIdx.x;
    int bx = blockIdx.x;
    int b = bx >> 8, c = bx & (NC - 1);
    float Ar = abar[2 * n], Ai = abar[2 * n + 1];
    float hr = 0.f, hi = 0.f;
    size_t base = (size_t)(b * SEQ + c * LC) * N2 + 2 * n;
#pragma unroll
    for (int i = 0; i < LC; ++i) {
        float2 x = *(const float2*)&Bu[base + (size_t)i * N2];
        float nhr = fmaf(Ar, hr, fmaf(-Ai, hi, x.x));
        float nhi = fmaf(Ar, hi, fmaf(Ai, hr, x.y));
        hr = nhr; hi = nhi;
        *(float2*)&Bu[base + (size_t)i * N2] = make_float2(hr, hi);
    }
    *(float2*)&E[((b * NC + c) * 64 + n) * 2] = make_float2(hr, hi);
}

// Scan phase B: sequential prefix over chunk carries.
__global__ __launch_bounds__(64) void scan_carry_kernel(
    const float* __restrict__ E, const float* __restrict__ powtab,
    float* __restrict__ P)
{
    int n = threadIdx.x;
    int b = blockIdx.x;
    float aLr = powtab[((LC - 1) * 64 + n) * 2];
    float aLi = powtab[((LC - 1) * 64 + n) * 2 + 1];
    float pr = 0.f, pi = 0.f;
    for (int c = 0; c < NC; ++c) {
        int idx = ((b * NC + c) * 64 + n) * 2;
        P[idx] = pr; P[idx + 1] = pi;
        float2 e = *(const float2*)&E[idx];
        float npr = fmaf(aLr, pr, fmaf(-aLi, pi, e.x));
        float npi = fmaf(aLr, pi, fmaf(aLi, pr, e.y));
        pr = npr; pi = npi;
    }
}

// Scan phase C: H[t] += a^(i+1) * P[chunk], in place in Bu.
__global__ __launch_bounds__(64) void scan_fix_kernel(
    float* Bu, const float* __restrict__ P, const float* __restrict__ powtab)
{
    int n = threadIdx.x;
    int bx = blockIdx.x;
    int b = bx >> 8, c = bx & (NC - 1);
    if (c == 0) return;
    float2 p = *(const float2*)&P[((b * NC + c) * 64 + n) * 2];
    size_t base = (size_t)(b * SEQ + c * LC) * N2 + 2 * n;
#pragma unroll
    for (int i = 0; i < LC; ++i) {
        float2 wv = *(const float2*)&powtab[(i * 64 + n) * 2];
        float cr = wv.x * p.x - wv.y * p.y;
        float ci = fmaf(wv.x, p.y, wv.y * p.x);
        float2 hcur = *(const float2*)&Bu[base + (size_t)i * N2];
        hcur.x += cr; hcur.y += ci;
        *(float2*)&Bu[base + (size_t)i * N2] = hcur;
    }
}

// ---------------------------------------------------------------------------
extern "C" void kernel_launch(void* const* d_in, const int* in_sizes, int n_in,
                              void* d_out, int out_size, void* d_ws, size_t ws_size,
                              hipStream_t stream)
{
    const float* u   = (const float*)d_in[0];
    const float* lar = (const float*)d_in[1];
    const float* lai = (const float*)d_in[2];
    const float* Bw  = (const float*)d_in[3];
    const float* Cw  = (const float*)d_in[4];
    const float* Dw  = (const float*)d_in[5];
    float* y = (float*)d_out;
    char* ws = (char*)d_ws;

    float*          abar   = (float*)(ws + OFFB_ABAR);
    float*          powtab = (float*)(ws + OFFB_POWTAB);
    unsigned short* Bwpb   = (unsigned short*)(ws + OFFB_BWPB);
    unsigned short* W2b    = (unsigned short*)(ws + OFFB_W2B);
    float*          Bu     = (float*)(ws + OFFB_BU);
    float*          E      = (float*)(ws + OFFB_E);
    float*          P      = (float*)(ws + OFFB_P);

    hipLaunchKernelGGL(prep_kernel, dim3(128), dim3(256), 0, stream,
                       lar, lai, Bw, Cw, Dw, abar, powtab, Bwpb, W2b);
    // GEMM1: Bu[32768][128] = u @ Bwpb^T
    hipLaunchKernelGGL(gemm_bf16_kernel, dim3(MTOT / 128, 1), dim3(256), 0, stream,
                       u, D_MODEL, D_MODEL, u, 0, 0, Bwpb, D_MODEL, Bu, N2);
    hipLaunchKernelGGL(scan_local_kernel, dim3(BATCH * NC), dim3(64), 0, stream,
                       Bu, abar, E);
    hipLaunchKernelGGL(scan_carry_kernel, dim3(BATCH), dim3(64), 0, stream,
                       E, powtab, P);
    hipLaunchKernelGGL(scan_fix_kernel, dim3(BATCH * NC), dim3(64), 0, stream,
                       Bu, P, powtab);
    // GEMM2: y[32768][512] = [u | H] @ [Dw | Cwp]^T
    hipLaunchKernelGGL(gemm_bf16_kernel, dim3(MTOT / 128, D_MODEL / 128), dim3(256), 0, stream,
                       u, D_MODEL, D_MODEL, Bu, N2, N2, W2b, 640, y, D_MODEL);
}

// Round 4
// 185.730 us; speedup vs baseline: 2.4265x; 1.0919x over previous
//
#include <hip/hip_runtime.h>
#include <hip/hip_bf16.h>

// S4D layer, round 4: fused-scan bf16-MFMA pipeline.
//  prep                     : A_bar, powtab (a^(i+1)), permuted bf16 weights
//  gemm1_fused              : Bu = u @ Bwp^T (MFMA) -> in-LDS local chunk scan
//                             -> H_loc (bf16) + chunk-end states E; also emits u_bf
//  scan_carry_par           : Kogge-Stone prefix over chunk carries (E -> P)
//  gemm2_fused<A1BF>        : y = [u | Hfix] @ [Dw | Cwp]^T, fixup H_loc + a^(i+1)*P
//                             applied during A2 staging; A1 staged from u_bf via
//                             global_load_lds when workspace allows.

#define D_MODEL 512
#define N2      128
#define BATCH   8
#define SEQ     4096
#define MTOT    (BATCH*SEQ)    // 32768
#define LC      16
#define NC      (SEQ/LC)       // 256
#define PADW    132            // padded LDS row stride (floats) for scan tile

// ---- workspace byte offsets ----
#define OFFB_ABAR   0u
#define OFFB_POWTAB 512u          // 16*64*2*4 = 8192
#define OFFB_BWPB   16384u        // 128*512*2 = 131072
#define OFFB_W2B    147456u       // 512*640*2 = 655360 -> ends 802816
#define OFFB_E      1048576u      // 8*64*256*2*4 = 1 MB
#define OFFB_P      2097152u      // 8*256*128*4  = 1 MB
#define OFFB_HLOC   3145728u      // 32768*128*2  = 8 MB -> ends 11534336
#define OFFB_UBF    11534336u     // 32768*512*2  = 32 MB -> ends 45088768
#define WS_NEED_UBF 45088768u

typedef __bf16  bf16x8  __attribute__((ext_vector_type(8)));
typedef float   f32x4   __attribute__((ext_vector_type(4)));
typedef unsigned short ushort8 __attribute__((ext_vector_type(8)));

__device__ __forceinline__ unsigned short f2bf(float f) {
    union { float f; unsigned int u; } v; v.f = f;
    unsigned int r = v.u + 0x7fffu + ((v.u >> 16) & 1u);   // RNE
    return (unsigned short)(r >> 16);
}
__device__ __forceinline__ float bf2f(unsigned short s) {
    union { unsigned int u; float f; } v; v.u = ((unsigned int)s) << 16;
    return v.f;
}
__device__ __forceinline__ void gload_lds16(const void* g, void* l) {
    __builtin_amdgcn_global_load_lds(
        (const __attribute__((address_space(1))) void*)g,
        (__attribute__((address_space(3))) void*)l, 16, 0, 0);
}

// ---------------------------------------------------------------------------
// prep
// ---------------------------------------------------------------------------
__global__ __launch_bounds__(256) void prep_kernel(
    const float* __restrict__ lar, const float* __restrict__ lai,
    const float* __restrict__ Bw,  const float* __restrict__ Cw,
    const float* __restrict__ Dw,
    float* __restrict__ abar, float* __restrict__ powtab,
    unsigned short* __restrict__ Bwpb, unsigned short* __restrict__ W2b)
{
    int tid = blockIdx.x * blockDim.x + threadIdx.x;
    if (blockIdx.x == 0 && threadIdx.x < 64) {
        int n = threadIdx.x;
        float ar = -expf(lar[n]);
        float ai = lai[n];
        const float h = 0.5f;
        float nr = 1.f + h * ar, ni = h * ai;
        float dr = 1.f - h * ar, di = -h * ai;
        float den = dr * dr + di * di;
        float Ar = (nr * dr + ni * di) / den;
        float Ai = (ni * dr - nr * di) / den;
        abar[2 * n] = Ar; abar[2 * n + 1] = Ai;
        float pr = Ar, pi = Ai;
        for (int i = 0; i < LC; ++i) {           // powtab[i][n] = a^(i+1)
            powtab[i * 128 + 2 * n]     = pr;
            powtab[i * 128 + 2 * n + 1] = pi;
            float npr = pr * Ar - pi * Ai;
            float npi = pr * Ai + pi * Ar;
            pr = npr; pi = npi;
        }
    }
    int stride = gridDim.x * blockDim.x;
    for (int idx = tid; idx < N2 * D_MODEL; idx += stride) {
        int np = idx / D_MODEL, k = idx % D_MODEL;
        int src = (np & 1) ? (64 + (np >> 1)) : (np >> 1);
        Bwpb[idx] = f2bf(Bw[src * D_MODEL + k]);
    }
    for (int idx = tid; idx < D_MODEL * 640; idx += stride) {
        int d = idx / 640, k = idx % 640;
        float v;
        if (k < D_MODEL) v = Dw[d * D_MODEL + k];
        else {
            int np = k - D_MODEL;
            int src = (np & 1) ? (64 + (np >> 1)) : (np >> 1);
            v = Cw[d * N2 + src];
        }
        W2b[idx] = f2bf(v);
    }
}

// ---------------------------------------------------------------------------
// gemm1_fused: 64x128 tile (64 t-rows, all 128 channels), K=512.
// Epilogue: acc -> LDS -> local chunk scans (4 chunks) -> H_loc bf16 + E.
// Also writes u_bf (bf16 copy of u) from the staging registers when enabled.
// ---------------------------------------------------------------------------
__global__ __launch_bounds__(256) void gemm1_fused(
    const float* __restrict__ u, const unsigned short* __restrict__ Bwpb,
    const float* __restrict__ abar,
    unsigned short* __restrict__ Hloc, float* __restrict__ E,
    unsigned short* __restrict__ u_bf, int write_ubf)
{
    __shared__ __align__(16) unsigned short As[64 * 64];
    __shared__ __align__(16) unsigned short Bs[128 * 64];
    __shared__ __align__(16) float Hs[64 * PADW];
    const int tid  = threadIdx.x;
    const int lane = tid & 63;
    const int w    = tid >> 6;
    const int wm   = (w >> 1) * 32;
    const int wn   = (w & 1) * 64;
    const int m0   = blockIdx.x * 64;

    f32x4 acc[2][4];
#pragma unroll
    for (int i = 0; i < 2; ++i)
#pragma unroll
        for (int j = 0; j < 4; ++j)
            acc[i][j] = (f32x4){0.f, 0.f, 0.f, 0.f};

    const int tr = tid >> 3, tc = tid & 7;

    for (int k0 = 0; k0 < D_MODEL; k0 += 64) {
        __syncthreads();
#pragma unroll
        for (int q = 0; q < 4; ++q) {            // B: 128 rows x 64 k
            int r = q * 32 + tr;
            int cs = tc ^ (r & 7);
            gload_lds16(Bwpb + (size_t)r * D_MODEL + k0 + cs * 8,
                        (char*)Bs + (q * 256 + tid) * 16);
        }
#pragma unroll
        for (int q = 0; q < 2; ++q) {            // A: 64 rows x 64 k, f32->bf16
            int r = q * 32 + tr;
            const float* src = u + (size_t)(m0 + r) * D_MODEL + k0 + tc * 8;
            float4 v0 = *(const float4*)src;
            float4 v1 = *(const float4*)(src + 4);
            ushort8 p;
            p[0] = f2bf(v0.x); p[1] = f2bf(v0.y); p[2] = f2bf(v0.z); p[3] = f2bf(v0.w);
            p[4] = f2bf(v1.x); p[5] = f2bf(v1.y); p[6] = f2bf(v1.z); p[7] = f2bf(v1.w);
            int cd = tc ^ (r & 7);
            *(ushort8*)((char*)As + r * 128 + cd * 16) = p;
            if (write_ubf)
                *(ushort8*)&u_bf[(size_t)(m0 + r) * D_MODEL + k0 + tc * 8] = p;
        }
        __syncthreads();
#pragma unroll
        for (int kk = 0; kk < 2; ++kk) {
            bf16x8 a[2], b[4];
#pragma unroll
            for (int i = 0; i < 2; ++i) {
                int row = wm + i * 16 + (lane & 15);
                int kb  = kk * 64 + ((lane >> 4) << 4);
                a[i] = *(const bf16x8*)((const char*)As + row * 128 + (kb ^ ((row & 7) << 4)));
            }
#pragma unroll
            for (int j = 0; j < 4; ++j) {
                int row = wn + j * 16 + (lane & 15);
                int kb  = kk * 64 + ((lane >> 4) << 4);
                b[j] = *(const bf16x8*)((const char*)Bs + row * 128 + (kb ^ ((row & 7) << 4)));
            }
#pragma unroll
            for (int i = 0; i < 2; ++i)
#pragma unroll
                for (int j = 0; j < 4; ++j)
                    acc[i][j] = __builtin_amdgcn_mfma_f32_16x16x32_bf16(a[i], b[j], acc[i][j], 0, 0, 0);
        }
    }

    // ---- epilogue: acc -> Hs ----
#pragma unroll
    for (int i = 0; i < 2; ++i)
#pragma unroll
        for (int j = 0; j < 4; ++j) {
            int col = wn + j * 16 + (lane & 15);
#pragma unroll
            for (int r = 0; r < 4; ++r) {
                int row = wm + i * 16 + ((lane >> 4) << 2) + r;
                Hs[row * PADW + col] = acc[i][j][r];
            }
        }
    __syncthreads();

    // ---- local chunk scans: 64 chains x 4 chunks, one task per thread ----
    {
        int n  = tid & 63;
        int cl = tid >> 6;                       // 0..3
        float2 ab = *(const float2*)&abar[2 * n];
        float hr = 0.f, hi = 0.f;
#pragma unroll
        for (int i = 0; i < LC; ++i) {
            int t = cl * LC + i;
            float xr = Hs[t * PADW + 2 * n];
            float xi = Hs[t * PADW + 2 * n + 1];
            float nhr = fmaf(ab.x, hr, fmaf(-ab.y, hi, xr));
            float nhi = fmaf(ab.x, hi, fmaf(ab.y, hr, xi));
            hr = nhr; hi = nhi;
            Hs[t * PADW + 2 * n]     = hr;
            Hs[t * PADW + 2 * n + 1] = hi;
        }
        int b  = m0 >> 12;
        int c0 = (m0 & 4095) >> 4;
        *(float2*)&E[((size_t)(b * 64 + n) * NC + c0 + cl) * 2] = make_float2(hr, hi);
    }
    __syncthreads();

    // ---- Hs -> H_loc (bf16) ----
#pragma unroll
    for (int q = 0; q < 2; ++q) {
        int r = q * 32 + tr;
        int cb = tc * 16;
        const float* row = &Hs[r * PADW + cb];
        ushort8 o0, o1;
#pragma unroll
        for (int j = 0; j < 8; ++j) o0[j] = f2bf(row[j]);
#pragma unroll
        for (int j = 0; j < 8; ++j) o1[j] = f2bf(row[8 + j]);
        *(ushort8*)&Hloc[(size_t)(m0 + r) * N2 + cb]     = o0;
        *(ushort8*)&Hloc[(size_t)(m0 + r) * N2 + cb + 8] = o1;
    }
}

// ---------------------------------------------------------------------------
// scan_carry_par: per (b,n) chain, prefix over NC=256 chunk carries.
// 4 segments of 64 chunks; Kogge-Stone via __shfl_up within each segment.
// S_c = aL*S_{c-1} + e_c, aL = abar^LC. Writes exclusive prefix P[b][c][2n].
// ---------------------------------------------------------------------------
__global__ __launch_bounds__(256) void scan_carry_par(
    const float* __restrict__ E, const float* __restrict__ abar,
    float* __restrict__ P)
{
    const int b    = blockIdx.x;          // 8
    const int wv   = threadIdx.x >> 6;    // 4 waves
    const int lane = threadIdx.x & 63;

    for (int n = wv * 16; n < wv * 16 + 16; ++n) {
        float2 ab = *(const float2*)&abar[2 * n];
        float ar = ab.x, ai = ab.y;
        for (int k = 0; k < 4; ++k) {     // aL = ab^16
            float t = ar * ar - ai * ai;  ai = 2.f * ar * ai;  ar = t;
        }
        float pr[7], pi[7];               // aL^(2^k), k=0..6
        pr[0] = ar; pi[0] = ai;
#pragma unroll
        for (int k = 1; k < 7; ++k) {
            pr[k] = pr[k-1] * pr[k-1] - pi[k-1] * pi[k-1];
            pi[k] = 2.f * pr[k-1] * pi[k-1];
        }
        int L = lane + 1;                 // per-lane weight aL^(lane+1)
        float wr = 1.f, wi = 0.f;
#pragma unroll
        for (int k = 0; k < 7; ++k) if ((L >> k) & 1) {
            float t = wr * pr[k] - wi * pi[k];
            wi = wr * pi[k] + wi * pr[k]; wr = t;
        }
        const float* Eb = E + (size_t)(b * 64 + n) * NC * 2;
        float cr = 0.f, ci = 0.f;         // carry into segment
        for (int s = 0; s < 4; ++s) {
            float2 e = *(const float2*)&Eb[(s * 64 + lane) * 2];
            float xr = e.x, xi = e.y;
#pragma unroll
            for (int k = 0; k < 6; ++k) {
                int d = 1 << k;
                float tr_ = __shfl_up(xr, (unsigned)d);
                float ti_ = __shfl_up(xi, (unsigned)d);
                if (lane >= d) {
                    xr = fmaf(pr[k], tr_, fmaf(-pi[k], ti_, xr));
                    xi = fmaf(pr[k], ti_, fmaf(pi[k], tr_, xi));
                }
            }
            float gr = fmaf(wr, cr, fmaf(-wi, ci, xr));   // global inclusive
            float gi = fmaf(wr, ci, fmaf(wi, cr, xi));
            float exr = __shfl_up(gr, 1u);
            float exi = __shfl_up(gi, 1u);
            if (lane == 0) { exr = cr; exi = ci; }
            *(float2*)&P[(size_t)(b * NC + s * 64 + lane) * N2 + 2 * n] =
                make_float2(exr, exi);
            cr = __shfl(gr, 63);
            ci = __shfl(gi, 63);
        }
    }
}

// ---------------------------------------------------------------------------
// gemm2_fused: y[m][d] = [u | Hfix][m] . W2b[d], 128x128 tile, Ktot=640.
// A1 (k<512): u as bf16 (gload_lds from u_bf) or f32-convert fallback.
// A2 (k>=512): Hfix = H_loc + a^(i+1) * P[b][chunk], computed while staging.
// ---------------------------------------------------------------------------
template<bool A1BF>
__global__ __launch_bounds__(256) void gemm2_fused(
    const float* __restrict__ uf,
    const unsigned short* __restrict__ ubf,
    const unsigned short* __restrict__ Hloc,
    const unsigned short* __restrict__ W2b,
    const float* __restrict__ P,
    const float* __restrict__ powtab,
    float* __restrict__ y)
{
    __shared__ __align__(16) unsigned short As[128 * 64];
    __shared__ __align__(16) unsigned short Bs[128 * 64];
    const int tid  = threadIdx.x;
    const int lane = tid & 63;
    const int w    = tid >> 6;
    const int wm   = (w >> 1) * 64;
    const int wn   = (w & 1) * 64;
    const int m0   = blockIdx.x * 128;
    const int n0   = blockIdx.y * 128;

    f32x4 acc[4][4];
#pragma unroll
    for (int i = 0; i < 4; ++i)
#pragma unroll
        for (int j = 0; j < 4; ++j)
            acc[i][j] = (f32x4){0.f, 0.f, 0.f, 0.f};

    const int tr = tid >> 3, tc = tid & 7;

    for (int k0 = 0; k0 < 640; k0 += 64) {
        __syncthreads();
#pragma unroll
        for (int q = 0; q < 4; ++q) {            // B tile
            int r = q * 32 + tr;
            int cs = tc ^ (r & 7);
            gload_lds16(W2b + (size_t)(n0 + r) * 640 + k0 + cs * 8,
                        (char*)Bs + (q * 256 + tid) * 16);
        }
        if (k0 < D_MODEL) {                      // A1: u
            if constexpr (A1BF) {
#pragma unroll
                for (int q = 0; q < 4; ++q) {
                    int r = q * 32 + tr;
                    int cs = tc ^ (r & 7);
                    gload_lds16(ubf + (size_t)(m0 + r) * D_MODEL + k0 + cs * 8,
                                (char*)As + (q * 256 + tid) * 16);
                }
            } else {
#pragma unroll
                for (int q = 0; q < 4; ++q) {
                    int r = q * 32 + tr;
                    const float* src = uf + (size_t)(m0 + r) * D_MODEL + k0 + tc * 8;
                    float4 v0 = *(const float4*)src;
                    float4 v1 = *(const float4*)(src + 4);
                    ushort8 p;
                    p[0] = f2bf(v0.x); p[1] = f2bf(v0.y); p[2] = f2bf(v0.z); p[3] = f2bf(v0.w);
                    p[4] = f2bf(v1.x); p[5] = f2bf(v1.y); p[6] = f2bf(v1.z); p[7] = f2bf(v1.w);
                    int cd = tc ^ (r & 7);
                    *(ushort8*)((char*)As + r * 128 + cd * 16) = p;
                }
            }
        } else {                                 // A2: Hfix
            const int kk0 = k0 - D_MODEL;
#pragma unroll
            for (int q = 0; q < 4; ++q) {
                int r = q * 32 + tr;
                int m = m0 + r;
                int b = m >> 12, t = m & 4095;
                int c = t >> 4, i = t & 15;
                ushort8 hl = *(const ushort8*)&Hloc[(size_t)m * N2 + kk0 + tc * 8];
                const float* Pp = P + (size_t)(b * NC + c) * N2 + kk0 + tc * 8;
                float4 p0 = *(const float4*)Pp;
                float4 p1 = *(const float4*)(Pp + 4);
                const float* Wp = powtab + i * 128 + kk0 + tc * 8;
                float4 w0 = *(const float4*)Wp;
                float4 w1 = *(const float4*)(Wp + 4);
                ushort8 p;
                p[0] = f2bf(fmaf(w0.x, p0.x, fmaf(-w0.y, p0.y, bf2f(hl[0]))));
                p[1] = f2bf(fmaf(w0.x, p0.y, fmaf( w0.y, p0.x, bf2f(hl[1]))));
                p[2] = f2bf(fmaf(w0.z, p0.z, fmaf(-w0.w, p0.w, bf2f(hl[2]))));
                p[3] = f2bf(fmaf(w0.z, p0.w, fmaf( w0.w, p0.z, bf2f(hl[3]))));
                p[4] = f2bf(fmaf(w1.x, p1.x, fmaf(-w1.y, p1.y, bf2f(hl[4]))));
                p[5] = f2bf(fmaf(w1.x, p1.y, fmaf( w1.y, p1.x, bf2f(hl[5]))));
                p[6] = f2bf(fmaf(w1.z, p1.z, fmaf(-w1.w, p1.w, bf2f(hl[6]))));
                p[7] = f2bf(fmaf(w1.z, p1.w, fmaf( w1.w, p1.z, bf2f(hl[7]))));
                int cd = tc ^ (r & 7);
                *(ushort8*)((char*)As + r * 128 + cd * 16) = p;
            }
        }
        __syncthreads();
#pragma unroll
        for (int kk = 0; kk < 2; ++kk) {
            bf16x8 a[4], b[4];
#pragma unroll
            for (int i = 0; i < 4; ++i) {
                int row = wm + i * 16 + (lane & 15);
                int kb  = kk * 64 + ((lane >> 4) << 4);
                a[i] = *(const bf16x8*)((const char*)As + row * 128 + (kb ^ ((row & 7) << 4)));
            }
#pragma unroll
            for (int j = 0; j < 4; ++j) {
                int row = wn + j * 16 + (lane & 15);
                int kb  = kk * 64 + ((lane >> 4) << 4);
                b[j] = *(const bf16x8*)((const char*)Bs + row * 128 + (kb ^ ((row & 7) << 4)));
            }
#pragma unroll
            for (int i = 0; i < 4; ++i)
#pragma unroll
                for (int j = 0; j < 4; ++j)
                    acc[i][j] = __builtin_amdgcn_mfma_f32_16x16x32_bf16(a[i], b[j], acc[i][j], 0, 0, 0);
        }
    }

#pragma unroll
    for (int i = 0; i < 4; ++i)
#pragma unroll
        for (int j = 0; j < 4; ++j) {
            int col = n0 + wn + j * 16 + (lane & 15);
#pragma unroll
            for (int r = 0; r < 4; ++r) {
                int row = m0 + wm + i * 16 + ((lane >> 4) << 2) + r;
                y[(size_t)row * D_MODEL + col] = acc[i][j][r];
            }
        }
}

// ---------------------------------------------------------------------------
extern "C" void kernel_launch(void* const* d_in, const int* in_sizes, int n_in,
                              void* d_out, int out_size, void* d_ws, size_t ws_size,
                              hipStream_t stream)
{
    const float* u   = (const float*)d_in[0];
    const float* lar = (const float*)d_in[1];
    const float* lai = (const float*)d_in[2];
    const float* Bw  = (const float*)d_in[3];
    const float* Cw  = (const float*)d_in[4];
    const float* Dw  = (const float*)d_in[5];
    float* y = (float*)d_out;
    char* ws = (char*)d_ws;

    float*          abar   = (float*)(ws + OFFB_ABAR);
    float*          powtab = (float*)(ws + OFFB_POWTAB);
    unsigned short* Bwpb   = (unsigned short*)(ws + OFFB_BWPB);
    unsigned short* W2b    = (unsigned short*)(ws + OFFB_W2B);
    float*          E      = (float*)(ws + OFFB_E);
    float*          P      = (float*)(ws + OFFB_P);
    unsigned short* Hloc   = (unsigned short*)(ws + OFFB_HLOC);
    unsigned short* u_bf   = (unsigned short*)(ws + OFFB_UBF);

    const int use_ubf = (ws_size >= (size_t)WS_NEED_UBF) ? 1 : 0;

    hipLaunchKernelGGL(prep_kernel, dim3(128), dim3(256), 0, stream,
                       lar, lai, Bw, Cw, Dw, abar, powtab, Bwpb, W2b);
    hipLaunchKernelGGL(gemm1_fused, dim3(MTOT / 64), dim3(256), 0, stream,
                       u, Bwpb, abar, Hloc, E, u_bf, use_ubf);
    hipLaunchKernelGGL(scan_carry_par, dim3(BATCH), dim3(256), 0, stream,
                       E, abar, P);
    if (use_ubf) {
        hipLaunchKernelGGL((gemm2_fused<true>), dim3(MTOT / 128, D_MODEL / 128),
                           dim3(256), 0, stream,
                           u, u_bf, Hloc, W2b, P, powtab, y);
    } else {
        hipLaunchKernelGGL((gemm2_fused<false>), dim3(MTOT / 128, D_MODEL / 128),
                           dim3(256), 0, stream,
                           u, u_bf, Hloc, W2b, P, powtab, y);
    }
}

// Round 5
// 175.805 us; speedup vs baseline: 2.5635x; 1.0565x over previous
//
#include <hip/hip_runtime.h>
#include <hip/hip_bf16.h>

// S4D layer, round 5: 2-phase double-buffered MFMA GEMMs, no u_bf, wide carry scan.
//  prep           : A_bar, powtab (a^(i+1)), permuted bf16 weights
//  gemm1_fused    : Bu = u @ Bwp^T (MFMA, dbuf) -> in-LDS local chunk scan
//                   -> H_loc (bf16) + chunk-end states E
//  scan_carry_par : Kogge-Stone prefix over chunk carries (E -> P), 64 blocks
//  gemm2_fused    : y = [u | Hfix] @ [Dw | Cwp]^T (MFMA, dbuf); fixup
//                   Hfix = H_loc + a^(i+1)*P applied during A2 staging.

#define D_MODEL 512
#define N2      128
#define BATCH   8
#define SEQ     4096
#define MTOT    (BATCH*SEQ)    // 32768
#define LC      16
#define NC      (SEQ/LC)       // 256
#define PADW    132            // padded LDS row stride (floats) for scan tile

// ---- workspace byte offsets ----
#define OFFB_ABAR   0u
#define OFFB_POWTAB 512u          // 16*64*2*4 = 8192
#define OFFB_BWPB   16384u        // 128*512*2 = 131072
#define OFFB_W2B    147456u       // 512*640*2 = 655360 -> ends 802816
#define OFFB_E      1048576u      // 8*64*256*2*4 = 1 MB
#define OFFB_P      2097152u      // 8*256*128*4  = 1 MB
#define OFFB_HLOC   3145728u      // 32768*128*2  = 8 MB -> ends 11534336

typedef __bf16  bf16x8  __attribute__((ext_vector_type(8)));
typedef float   f32x4   __attribute__((ext_vector_type(4)));
typedef unsigned short ushort8 __attribute__((ext_vector_type(8)));

__device__ __forceinline__ unsigned short f2bf(float f) {
    union { float f; unsigned int u; } v; v.f = f;
    unsigned int r = v.u + 0x7fffu + ((v.u >> 16) & 1u);   // RNE
    return (unsigned short)(r >> 16);
}
__device__ __forceinline__ float bf2f(unsigned short s) {
    union { unsigned int u; float f; } v; v.u = ((unsigned int)s) << 16;
    return v.f;
}
__device__ __forceinline__ void gload_lds16(const void* g, void* l) {
    __builtin_amdgcn_global_load_lds(
        (const __attribute__((address_space(1))) void*)g,
        (__attribute__((address_space(3))) void*)l, 16, 0, 0);
}

// ---------------------------------------------------------------------------
// prep
// ---------------------------------------------------------------------------
__global__ __launch_bounds__(256) void prep_kernel(
    const float* __restrict__ lar, const float* __restrict__ lai,
    const float* __restrict__ Bw,  const float* __restrict__ Cw,
    const float* __restrict__ Dw,
    float* __restrict__ abar, float* __restrict__ powtab,
    unsigned short* __restrict__ Bwpb, unsigned short* __restrict__ W2b)
{
    int tid = blockIdx.x * blockDim.x + threadIdx.x;
    if (blockIdx.x == 0 && threadIdx.x < 64) {
        int n = threadIdx.x;
        float ar = -expf(lar[n]);
        float ai = lai[n];
        const float h = 0.5f;
        float nr = 1.f + h * ar, ni = h * ai;
        float dr = 1.f - h * ar, di = -h * ai;
        float den = dr * dr + di * di;
        float Ar = (nr * dr + ni * di) / den;
        float Ai = (ni * dr - nr * di) / den;
        abar[2 * n] = Ar; abar[2 * n + 1] = Ai;
        float pr = Ar, pi = Ai;
        for (int i = 0; i < LC; ++i) {           // powtab[i][n] = a^(i+1)
            powtab[i * 128 + 2 * n]     = pr;
            powtab[i * 128 + 2 * n + 1] = pi;
            float npr = pr * Ar - pi * Ai;
            float npi = pr * Ai + pi * Ar;
            pr = npr; pi = npi;
        }
    }
    int stride = gridDim.x * blockDim.x;
    for (int idx = tid; idx < N2 * D_MODEL; idx += stride) {
        int np = idx / D_MODEL, k = idx % D_MODEL;
        int src = (np & 1) ? (64 + (np >> 1)) : (np >> 1);
        Bwpb[idx] = f2bf(Bw[src * D_MODEL + k]);
    }
    for (int idx = tid; idx < D_MODEL * 640; idx += stride) {
        int d = idx / 640, k = idx % 640;
        float v;
        if (k < D_MODEL) v = Dw[d * D_MODEL + k];
        else {
            int np = k - D_MODEL;
            int src = (np & 1) ? (64 + (np >> 1)) : (np >> 1);
            v = Cw[d * N2 + src];
        }
        W2b[idx] = f2bf(v);
    }
}

// ---------------------------------------------------------------------------
// gemm1_fused: 64x128 tile, K=512, double-buffered 2-phase pipeline.
// Epilogue: acc -> LDS -> local chunk scans (4 chunks) -> H_loc bf16 + E.
// ---------------------------------------------------------------------------
__global__ __launch_bounds__(256) void gemm1_fused(
    const float* __restrict__ u, const unsigned short* __restrict__ Bwpb,
    const float* __restrict__ abar,
    unsigned short* __restrict__ Hloc, float* __restrict__ E)
{
    __shared__ __align__(16) char smem[49152];
    unsigned short* As0 = (unsigned short*)smem;            // 8 KB
    unsigned short* As1 = (unsigned short*)(smem + 8192);   // 8 KB
    unsigned short* Bs0 = (unsigned short*)(smem + 16384);  // 16 KB
    unsigned short* Bs1 = (unsigned short*)(smem + 32768);  // 16 KB
    float* Hs = (float*)smem;   // epilogue overlay, 64*PADW*4 = 33792 B

    const int tid  = threadIdx.x;
    const int lane = tid & 63;
    const int w    = tid >> 6;
    const int wm   = (w >> 1) * 32;
    const int wn   = (w & 1) * 64;
    const int m0   = blockIdx.x * 64;
    const int tr = tid >> 3, tc = tid & 7;

    f32x4 acc[2][4];
#pragma unroll
    for (int i = 0; i < 2; ++i)
#pragma unroll
        for (int j = 0; j < 4; ++j)
            acc[i][j] = (f32x4){0.f, 0.f, 0.f, 0.f};

    auto stage = [&](int t, unsigned short* Asb, unsigned short* Bsb) {
        const int k0 = t * 64;
#pragma unroll
        for (int q = 0; q < 4; ++q) {            // B: 128 rows x 64 k
            int r = q * 32 + tr;
            int cs = tc ^ (r & 7);
            gload_lds16(Bwpb + (size_t)r * D_MODEL + k0 + cs * 8,
                        (char*)Bsb + (q * 256 + tid) * 16);
        }
#pragma unroll
        for (int q = 0; q < 2; ++q) {            // A: 64 rows x 64 k, f32->bf16
            int r = q * 32 + tr;
            const float* src = u + (size_t)(m0 + r) * D_MODEL + k0 + tc * 8;
            float4 v0 = *(const float4*)src;
            float4 v1 = *(const float4*)(src + 4);
            ushort8 p;
            p[0] = f2bf(v0.x); p[1] = f2bf(v0.y); p[2] = f2bf(v0.z); p[3] = f2bf(v0.w);
            p[4] = f2bf(v1.x); p[5] = f2bf(v1.y); p[6] = f2bf(v1.z); p[7] = f2bf(v1.w);
            int cd = tc ^ (r & 7);
            *(ushort8*)((char*)Asb + r * 128 + cd * 16) = p;
        }
    };
    auto compute = [&](const unsigned short* Asb, const unsigned short* Bsb) {
#pragma unroll
        for (int kk = 0; kk < 2; ++kk) {
            bf16x8 a[2], b[4];
#pragma unroll
            for (int i = 0; i < 2; ++i) {
                int row = wm + i * 16 + (lane & 15);
                int kb  = kk * 64 + ((lane >> 4) << 4);
                a[i] = *(const bf16x8*)((const char*)Asb + row * 128 + (kb ^ ((row & 7) << 4)));
            }
#pragma unroll
            for (int j = 0; j < 4; ++j) {
                int row = wn + j * 16 + (lane & 15);
                int kb  = kk * 64 + ((lane >> 4) << 4);
                b[j] = *(const bf16x8*)((const char*)Bsb + row * 128 + (kb ^ ((row & 7) << 4)));
            }
#pragma unroll
            for (int i = 0; i < 2; ++i)
#pragma unroll
                for (int j = 0; j < 4; ++j)
                    acc[i][j] = __builtin_amdgcn_mfma_f32_16x16x32_bf16(a[i], b[j], acc[i][j], 0, 0, 0);
        }
    };

    unsigned short *Ac = As0, *Bc = Bs0, *An = As1, *Bn = Bs1;
    stage(0, Ac, Bc);
    for (int t = 0; t < 8; ++t) {
        __syncthreads();                 // staged(t) ready; compute(t-1) done
        if (t + 1 < 8) stage(t + 1, An, Bn);
        compute(Ac, Bc);
        unsigned short* s;
        s = Ac; Ac = An; An = s;
        s = Bc; Bc = Bn; Bn = s;
    }

    // ---- epilogue: acc -> Hs (overlays staging LDS; barrier first) ----
    __syncthreads();
#pragma unroll
    for (int i = 0; i < 2; ++i)
#pragma unroll
        for (int j = 0; j < 4; ++j) {
            int col = wn + j * 16 + (lane & 15);
#pragma unroll
            for (int r = 0; r < 4; ++r) {
                int row = wm + i * 16 + ((lane >> 4) << 2) + r;
                Hs[row * PADW + col] = acc[i][j][r];
            }
        }
    __syncthreads();

    // ---- local chunk scans: 64 chains x 4 chunks, one task per thread ----
    {
        int n  = tid & 63;
        int cl = tid >> 6;                       // 0..3
        float2 ab = *(const float2*)&abar[2 * n];
        float hr = 0.f, hi = 0.f;
#pragma unroll
        for (int i = 0; i < LC; ++i) {
            int t = cl * LC + i;
            float xr = Hs[t * PADW + 2 * n];
            float xi = Hs[t * PADW + 2 * n + 1];
            float nhr = fmaf(ab.x, hr, fmaf(-ab.y, hi, xr));
            float nhi = fmaf(ab.x, hi, fmaf(ab.y, hr, xi));
            hr = nhr; hi = nhi;
            Hs[t * PADW + 2 * n]     = hr;
            Hs[t * PADW + 2 * n + 1] = hi;
        }
        int b  = m0 >> 12;
        int c0 = (m0 & 4095) >> 4;
        *(float2*)&E[((size_t)(b * 64 + n) * NC + c0 + cl) * 2] = make_float2(hr, hi);
    }
    __syncthreads();

    // ---- Hs -> H_loc (bf16) ----
#pragma unroll
    for (int q = 0; q < 2; ++q) {
        int r = q * 32 + tr;
        int cb = tc * 16;
        const float* row = &Hs[r * PADW + cb];
        ushort8 o0, o1;
#pragma unroll
        for (int j = 0; j < 8; ++j) o0[j] = f2bf(row[j]);
#pragma unroll
        for (int j = 0; j < 8; ++j) o1[j] = f2bf(row[8 + j]);
        *(ushort8*)&Hloc[(size_t)(m0 + r) * N2 + cb]     = o0;
        *(ushort8*)&Hloc[(size_t)(m0 + r) * N2 + cb + 8] = o1;
    }
}

// ---------------------------------------------------------------------------
// scan_carry_par: grid (8 batches, 8 n-groups); per wave 2 chains.
// Kogge-Stone over 4 segments of 64 chunks. Writes exclusive prefix P.
// ---------------------------------------------------------------------------
__global__ __launch_bounds__(256) void scan_carry_par(
    const float* __restrict__ E, const float* __restrict__ abar,
    float* __restrict__ P)
{
    const int b    = blockIdx.x;
    const int g0   = blockIdx.y * 8;
    const int wv   = threadIdx.x >> 6;
    const int lane = threadIdx.x & 63;

    for (int n = g0 + wv * 2; n < g0 + wv * 2 + 2; ++n) {
        float2 ab = *(const float2*)&abar[2 * n];
        float ar = ab.x, ai = ab.y;
        for (int k = 0; k < 4; ++k) {     // aL = ab^16
            float t = ar * ar - ai * ai;  ai = 2.f * ar * ai;  ar = t;
        }
        float pr[7], pi[7];               // aL^(2^k)
        pr[0] = ar; pi[0] = ai;
#pragma unroll
        for (int k = 1; k < 7; ++k) {
            pr[k] = pr[k-1] * pr[k-1] - pi[k-1] * pi[k-1];
            pi[k] = 2.f * pr[k-1] * pi[k-1];
        }
        int L = lane + 1;                 // aL^(lane+1)
        float wr = 1.f, wi = 0.f;
#pragma unroll
        for (int k = 0; k < 7; ++k) if ((L >> k) & 1) {
            float t = wr * pr[k] - wi * pi[k];
            wi = wr * pi[k] + wi * pr[k]; wr = t;
        }
        const float* Eb = E + (size_t)(b * 64 + n) * NC * 2;
        float cr = 0.f, ci = 0.f;
        for (int s = 0; s < 4; ++s) {
            float2 e = *(const float2*)&Eb[(s * 64 + lane) * 2];
            float xr = e.x, xi = e.y;
#pragma unroll
            for (int k = 0; k < 6; ++k) {
                int d = 1 << k;
                float tr_ = __shfl_up(xr, (unsigned)d);
                float ti_ = __shfl_up(xi, (unsigned)d);
                if (lane >= d) {
                    xr = fmaf(pr[k], tr_, fmaf(-pi[k], ti_, xr));
                    xi = fmaf(pr[k], ti_, fmaf(pi[k], tr_, xi));
                }
            }
            float gr = fmaf(wr, cr, fmaf(-wi, ci, xr));
            float gi = fmaf(wr, ci, fmaf(wi, cr, xi));
            float exr = __shfl_up(gr, 1u);
            float exi = __shfl_up(gi, 1u);
            if (lane == 0) { exr = cr; exi = ci; }
            *(float2*)&P[(size_t)(b * NC + s * 64 + lane) * N2 + 2 * n] =
                make_float2(exr, exi);
            cr = __shfl(gr, 63);
            ci = __shfl(gi, 63);
        }
    }
}

// ---------------------------------------------------------------------------
// gemm2_fused: y[m][d] = [u | Hfix][m] . W2b[d], 128x128 tile, Ktot=640,
// double-buffered 2-phase pipeline.
// ---------------------------------------------------------------------------
__global__ __launch_bounds__(256) void gemm2_fused(
    const float* __restrict__ uf,
    const unsigned short* __restrict__ Hloc,
    const unsigned short* __restrict__ W2b,
    const float* __restrict__ P,
    const float* __restrict__ powtab,
    float* __restrict__ y)
{
    __shared__ __align__(16) char smem[65536];
    unsigned short* As0 = (unsigned short*)smem;             // 16 KB
    unsigned short* As1 = (unsigned short*)(smem + 16384);
    unsigned short* Bs0 = (unsigned short*)(smem + 32768);
    unsigned short* Bs1 = (unsigned short*)(smem + 49152);

    const int tid  = threadIdx.x;
    const int lane = tid & 63;
    const int w    = tid >> 6;
    const int wm   = (w >> 1) * 64;
    const int wn   = (w & 1) * 64;
    const int m0   = blockIdx.x * 128;
    const int n0   = blockIdx.y * 128;
    const int tr = tid >> 3, tc = tid & 7;

    f32x4 acc[4][4];
#pragma unroll
    for (int i = 0; i < 4; ++i)
#pragma unroll
        for (int j = 0; j < 4; ++j)
            acc[i][j] = (f32x4){0.f, 0.f, 0.f, 0.f};

    auto stage = [&](int t, unsigned short* Asb, unsigned short* Bsb) {
        const int k0 = t * 64;
#pragma unroll
        for (int q = 0; q < 4; ++q) {            // B tile
            int r = q * 32 + tr;
            int cs = tc ^ (r & 7);
            gload_lds16(W2b + (size_t)(n0 + r) * 640 + k0 + cs * 8,
                        (char*)Bsb + (q * 256 + tid) * 16);
        }
        if (k0 < D_MODEL) {                      // A1: u f32 -> bf16
#pragma unroll
            for (int q = 0; q < 4; ++q) {
                int r = q * 32 + tr;
                const float* src = uf + (size_t)(m0 + r) * D_MODEL + k0 + tc * 8;
                float4 v0 = *(const float4*)src;
                float4 v1 = *(const float4*)(src + 4);
                ushort8 p;
                p[0] = f2bf(v0.x); p[1] = f2bf(v0.y); p[2] = f2bf(v0.z); p[3] = f2bf(v0.w);
                p[4] = f2bf(v1.x); p[5] = f2bf(v1.y); p[6] = f2bf(v1.z); p[7] = f2bf(v1.w);
                int cd = tc ^ (r & 7);
                *(ushort8*)((char*)Asb + r * 128 + cd * 16) = p;
            }
        } else {                                 // A2: Hfix = Hloc + a^(i+1)*P
            const int kk0 = k0 - D_MODEL;
#pragma unroll
            for (int q = 0; q < 4; ++q) {
                int r = q * 32 + tr;
                int m = m0 + r;
                int b = m >> 12, tt = m & 4095;
                int c = tt >> 4, i = tt & 15;
                ushort8 hl = *(const ushort8*)&Hloc[(size_t)m * N2 + kk0 + tc * 8];
                const float* Pp = P + (size_t)(b * NC + c) * N2 + kk0 + tc * 8;
                float4 p0 = *(const float4*)Pp;
                float4 p1 = *(const float4*)(Pp + 4);
                const float* Wp = powtab + i * 128 + kk0 + tc * 8;
                float4 w0 = *(const float4*)Wp;
                float4 w1 = *(const float4*)(Wp + 4);
                ushort8 p;
                p[0] = f2bf(fmaf(w0.x, p0.x, fmaf(-w0.y, p0.y, bf2f(hl[0]))));
                p[1] = f2bf(fmaf(w0.x, p0.y, fmaf( w0.y, p0.x, bf2f(hl[1]))));
                p[2] = f2bf(fmaf(w0.z, p0.z, fmaf(-w0.w, p0.w, bf2f(hl[2]))));
                p[3] = f2bf(fmaf(w0.z, p0.w, fmaf( w0.w, p0.z, bf2f(hl[3]))));
                p[4] = f2bf(fmaf(w1.x, p1.x, fmaf(-w1.y, p1.y, bf2f(hl[4]))));
                p[5] = f2bf(fmaf(w1.x, p1.y, fmaf( w1.y, p1.x, bf2f(hl[5]))));
                p[6] = f2bf(fmaf(w1.z, p1.z, fmaf(-w1.w, p1.w, bf2f(hl[6]))));
                p[7] = f2bf(fmaf(w1.z, p1.w, fmaf( w1.w, p1.z, bf2f(hl[7]))));
                int cd = tc ^ (r & 7);
                *(ushort8*)((char*)Asb + r * 128 + cd * 16) = p;
            }
        }
    };
    auto compute = [&](const unsigned short* Asb, const unsigned short* Bsb) {
#pragma unroll
        for (int kk = 0; kk < 2; ++kk) {
            bf16x8 a[4], b[4];
#pragma unroll
            for (int i = 0; i < 4; ++i) {
                int row = wm + i * 16 + (lane & 15);
                int kb  = kk * 64 + ((lane >> 4) << 4);
                a[i] = *(const bf16x8*)((const char*)Asb + row * 128 + (kb ^ ((row & 7) << 4)));
            }
#pragma unroll
            for (int j = 0; j < 4; ++j) {
                int row = wn + j * 16 + (lane & 15);
                int kb  = kk * 64 + ((lane >> 4) << 4);
                b[j] = *(const bf16x8*)((const char*)Bsb + row * 128 + (kb ^ ((row & 7) << 4)));
            }
#pragma unroll
            for (int i = 0; i < 4; ++i)
#pragma unroll
                for (int j = 0; j < 4; ++j)
                    acc[i][j] = __builtin_amdgcn_mfma_f32_16x16x32_bf16(a[i], b[j], acc[i][j], 0, 0, 0);
        }
    };

    unsigned short *Ac = As0, *Bc = Bs0, *An = As1, *Bn = Bs1;
    stage(0, Ac, Bc);
    for (int t = 0; t < 10; ++t) {
        __syncthreads();                 // staged(t) ready; compute(t-1) done
        if (t + 1 < 10) stage(t + 1, An, Bn);
        compute(Ac, Bc);
        unsigned short* s;
        s = Ac; Ac = An; An = s;
        s = Bc; Bc = Bn; Bn = s;
    }

#pragma unroll
    for (int i = 0; i < 4; ++i)
#pragma unroll
        for (int j = 0; j < 4; ++j) {
            int col = n0 + wn + j * 16 + (lane & 15);
#pragma unroll
            for (int r = 0; r < 4; ++r) {
                int row = m0 + wm + i * 16 + ((lane >> 4) << 2) + r;
                y[(size_t)row * D_MODEL + col] = acc[i][j][r];
            }
        }
}

// ---------------------------------------------------------------------------
extern "C" void kernel_launch(void* const* d_in, const int* in_sizes, int n_in,
                              void* d_out, int out_size, void* d_ws, size_t ws_size,
                              hipStream_t stream)
{
    const float* u   = (const float*)d_in[0];
    const float* lar = (const float*)d_in[1];
    const float* lai = (const float*)d_in[2];
    const float* Bw  = (const float*)d_in[3];
    const float* Cw  = (const float*)d_in[4];
    const float* Dw  = (const float*)d_in[5];
    float* y = (float*)d_out;
    char* ws = (char*)d_ws;

    float*          abar   = (float*)(ws + OFFB_ABAR);
    float*          powtab = (float*)(ws + OFFB_POWTAB);
    unsigned short* Bwpb   = (unsigned short*)(ws + OFFB_BWPB);
    unsigned short* W2b    = (unsigned short*)(ws + OFFB_W2B);
    float*          E      = (float*)(ws + OFFB_E);
    float*          P      = (float*)(ws + OFFB_P);
    unsigned short* Hloc   = (unsigned short*)(ws + OFFB_HLOC);

    hipLaunchKernelGGL(prep_kernel, dim3(128), dim3(256), 0, stream,
                       lar, lai, Bw, Cw, Dw, abar, powtab, Bwpb, W2b);
    hipLaunchKernelGGL(gemm1_fused, dim3(MTOT / 64), dim3(256), 0, stream,
                       u, Bwpb, abar, Hloc, E);
    hipLaunchKernelGGL(scan_carry_par, dim3(8, 8), dim3(256), 0, stream,
                       E, abar, P);
    hipLaunchKernelGGL(gemm2_fused, dim3(MTOT / 128, D_MODEL / 128),
                       dim3(256), 0, stream,
                       u, Hloc, W2b, P, powtab, y);
}

// Round 6
// 168.432 us; speedup vs baseline: 2.6757x; 1.0438x over previous
//
#include <hip/hip_runtime.h>
#include <hip/hip_bf16.h>

// S4D layer, round 6: dbuf 2-phase MFMA GEMMs + u_bf staging by-product.
//  prep           : A_bar, powtab (a^(i+1)), permuted bf16 weights
//  gemm1_fused    : Bu = u @ Bwp^T (MFMA, dbuf) -> in-LDS local chunk scan
//                   -> H_loc (bf16) + chunk-end E; also emits u_bf (bf16 u)
//  scan_carry_par : Kogge-Stone prefix over chunk carries (E -> P), 64 blocks
//  gemm2_fused    : y = [u | Hfix] @ [Dw | Cwp]^T (MFMA, dbuf); A1 staged from
//                   u_bf via global_load_lds; fixup Hfix = H_loc + a^(i+1)*P
//                   applied during A2 staging.

#define D_MODEL 512
#define N2      128
#define BATCH   8
#define SEQ     4096
#define MTOT    (BATCH*SEQ)    // 32768
#define LC      16
#define NC      (SEQ/LC)       // 256
#define PADW    132            // padded LDS row stride (floats) for scan tile

// ---- workspace byte offsets ----
#define OFFB_ABAR   0u
#define OFFB_POWTAB 512u          // 16*64*2*4 = 8192
#define OFFB_BWPB   16384u        // 128*512*2 = 131072
#define OFFB_W2B    147456u       // 512*640*2 = 655360 -> ends 802816
#define OFFB_E      1048576u      // 8*64*256*2*4 = 1 MB
#define OFFB_P      2097152u      // 8*256*128*4  = 1 MB
#define OFFB_HLOC   3145728u      // 32768*128*2  = 8 MB -> ends 11534336
#define OFFB_UBF    11534336u     // 32768*512*2  = 32 MB -> ends 45088768
#define WS_NEED_UBF 45088768u     // proven available (R4 ran the ubf path)

typedef __bf16  bf16x8  __attribute__((ext_vector_type(8)));
typedef float   f32x4   __attribute__((ext_vector_type(4)));
typedef unsigned short ushort8 __attribute__((ext_vector_type(8)));

__device__ __forceinline__ unsigned short f2bf(float f) {
    union { float f; unsigned int u; } v; v.f = f;
    unsigned int r = v.u + 0x7fffu + ((v.u >> 16) & 1u);   // RNE
    return (unsigned short)(r >> 16);
}
__device__ __forceinline__ float bf2f(unsigned short s) {
    union { unsigned int u; float f; } v; v.u = ((unsigned int)s) << 16;
    return v.f;
}
__device__ __forceinline__ void gload_lds16(const void* g, void* l) {
    __builtin_amdgcn_global_load_lds(
        (const __attribute__((address_space(1))) void*)g,
        (__attribute__((address_space(3))) void*)l, 16, 0, 0);
}

// ---------------------------------------------------------------------------
// prep
// ---------------------------------------------------------------------------
__global__ __launch_bounds__(256) void prep_kernel(
    const float* __restrict__ lar, const float* __restrict__ lai,
    const float* __restrict__ Bw,  const float* __restrict__ Cw,
    const float* __restrict__ Dw,
    float* __restrict__ abar, float* __restrict__ powtab,
    unsigned short* __restrict__ Bwpb, unsigned short* __restrict__ W2b)
{
    int tid = blockIdx.x * blockDim.x + threadIdx.x;
    if (blockIdx.x == 0 && threadIdx.x < 64) {
        int n = threadIdx.x;
        float ar = -expf(lar[n]);
        float ai = lai[n];
        const float h = 0.5f;
        float nr = 1.f + h * ar, ni = h * ai;
        float dr = 1.f - h * ar, di = -h * ai;
        float den = dr * dr + di * di;
        float Ar = (nr * dr + ni * di) / den;
        float Ai = (ni * dr - nr * di) / den;
        abar[2 * n] = Ar; abar[2 * n + 1] = Ai;
        float pr = Ar, pi = Ai;
        for (int i = 0; i < LC; ++i) {           // powtab[i][n] = a^(i+1)
            powtab[i * 128 + 2 * n]     = pr;
            powtab[i * 128 + 2 * n + 1] = pi;
            float npr = pr * Ar - pi * Ai;
            float npi = pr * Ai + pi * Ar;
            pr = npr; pi = npi;
        }
    }
    int stride = gridDim.x * blockDim.x;
    for (int idx = tid; idx < N2 * D_MODEL; idx += stride) {
        int np = idx / D_MODEL, k = idx % D_MODEL;
        int src = (np & 1) ? (64 + (np >> 1)) : (np >> 1);
        Bwpb[idx] = f2bf(Bw[src * D_MODEL + k]);
    }
    for (int idx = tid; idx < D_MODEL * 640; idx += stride) {
        int d = idx / 640, k = idx % 640;
        float v;
        if (k < D_MODEL) v = Dw[d * D_MODEL + k];
        else {
            int np = k - D_MODEL;
            int src = (np & 1) ? (64 + (np >> 1)) : (np >> 1);
            v = Cw[d * N2 + src];
        }
        W2b[idx] = f2bf(v);
    }
}

// ---------------------------------------------------------------------------
// gemm1_fused: 64x128 tile, K=512, double-buffered 2-phase pipeline.
// Emits u_bf (bf16 u) from staging registers. Epilogue: acc -> LDS ->
// local chunk scans (4 chunks) -> H_loc bf16 + E.
// ---------------------------------------------------------------------------
__global__ __launch_bounds__(256) void gemm1_fused(
    const float* __restrict__ u, const unsigned short* __restrict__ Bwpb,
    const float* __restrict__ abar,
    unsigned short* __restrict__ Hloc, float* __restrict__ E,
    unsigned short* __restrict__ u_bf, int write_ubf)
{
    __shared__ __align__(16) char smem[49152];
    unsigned short* As0 = (unsigned short*)smem;            // 8 KB
    unsigned short* As1 = (unsigned short*)(smem + 8192);   // 8 KB
    unsigned short* Bs0 = (unsigned short*)(smem + 16384);  // 16 KB
    unsigned short* Bs1 = (unsigned short*)(smem + 32768);  // 16 KB
    float* Hs = (float*)smem;   // epilogue overlay, 64*PADW*4 = 33792 B

    const int tid  = threadIdx.x;
    const int lane = tid & 63;
    const int w    = tid >> 6;
    const int wm   = (w >> 1) * 32;
    const int wn   = (w & 1) * 64;
    const int m0   = blockIdx.x * 64;
    const int tr = tid >> 3, tc = tid & 7;

    f32x4 acc[2][4];
#pragma unroll
    for (int i = 0; i < 2; ++i)
#pragma unroll
        for (int j = 0; j < 4; ++j)
            acc[i][j] = (f32x4){0.f, 0.f, 0.f, 0.f};

    auto stage = [&](int t, unsigned short* Asb, unsigned short* Bsb) {
        const int k0 = t * 64;
#pragma unroll
        for (int q = 0; q < 4; ++q) {            // B: 128 rows x 64 k
            int r = q * 32 + tr;
            int cs = tc ^ (r & 7);
            gload_lds16(Bwpb + (size_t)r * D_MODEL + k0 + cs * 8,
                        (char*)Bsb + (q * 256 + tid) * 16);
        }
#pragma unroll
        for (int q = 0; q < 2; ++q) {            // A: 64 rows x 64 k, f32->bf16
            int r = q * 32 + tr;
            const float* src = u + (size_t)(m0 + r) * D_MODEL + k0 + tc * 8;
            float4 v0 = *(const float4*)src;
            float4 v1 = *(const float4*)(src + 4);
            ushort8 p;
            p[0] = f2bf(v0.x); p[1] = f2bf(v0.y); p[2] = f2bf(v0.z); p[3] = f2bf(v0.w);
            p[4] = f2bf(v1.x); p[5] = f2bf(v1.y); p[6] = f2bf(v1.z); p[7] = f2bf(v1.w);
            int cd = tc ^ (r & 7);
            *(ushort8*)((char*)Asb + r * 128 + cd * 16) = p;
            if (write_ubf)
                *(ushort8*)&u_bf[(size_t)(m0 + r) * D_MODEL + k0 + tc * 8] = p;
        }
    };
    auto compute = [&](const unsigned short* Asb, const unsigned short* Bsb) {
#pragma unroll
        for (int kk = 0; kk < 2; ++kk) {
            bf16x8 a[2], b[4];
#pragma unroll
            for (int i = 0; i < 2; ++i) {
                int row = wm + i * 16 + (lane & 15);
                int kb  = kk * 64 + ((lane >> 4) << 4);
                a[i] = *(const bf16x8*)((const char*)Asb + row * 128 + (kb ^ ((row & 7) << 4)));
            }
#pragma unroll
            for (int j = 0; j < 4; ++j) {
                int row = wn + j * 16 + (lane & 15);
                int kb  = kk * 64 + ((lane >> 4) << 4);
                b[j] = *(const bf16x8*)((const char*)Bsb + row * 128 + (kb ^ ((row & 7) << 4)));
            }
#pragma unroll
            for (int i = 0; i < 2; ++i)
#pragma unroll
                for (int j = 0; j < 4; ++j)
                    acc[i][j] = __builtin_amdgcn_mfma_f32_16x16x32_bf16(a[i], b[j], acc[i][j], 0, 0, 0);
        }
    };

    unsigned short *Ac = As0, *Bc = Bs0, *An = As1, *Bn = Bs1;
    stage(0, Ac, Bc);
    for (int t = 0; t < 8; ++t) {
        __syncthreads();                 // staged(t) ready; compute(t-1) done
        if (t + 1 < 8) stage(t + 1, An, Bn);
        compute(Ac, Bc);
        unsigned short* s;
        s = Ac; Ac = An; An = s;
        s = Bc; Bc = Bn; Bn = s;
    }

    // ---- epilogue: acc -> Hs (overlays staging LDS; barrier first) ----
    __syncthreads();
#pragma unroll
    for (int i = 0; i < 2; ++i)
#pragma unroll
        for (int j = 0; j < 4; ++j) {
            int col = wn + j * 16 + (lane & 15);
#pragma unroll
            for (int r = 0; r < 4; ++r) {
                int row = wm + i * 16 + ((lane >> 4) << 2) + r;
                Hs[row * PADW + col] = acc[i][j][r];
            }
        }
    __syncthreads();

    // ---- local chunk scans: 64 chains x 4 chunks, one task per thread ----
    {
        int n  = tid & 63;
        int cl = tid >> 6;                       // 0..3
        float2 ab = *(const float2*)&abar[2 * n];
        float hr = 0.f, hi = 0.f;
#pragma unroll
        for (int i = 0; i < LC; ++i) {
            int t = cl * LC + i;
            float xr = Hs[t * PADW + 2 * n];
            float xi = Hs[t * PADW + 2 * n + 1];
            float nhr = fmaf(ab.x, hr, fmaf(-ab.y, hi, xr));
            float nhi = fmaf(ab.x, hi, fmaf(ab.y, hr, xi));
            hr = nhr; hi = nhi;
            Hs[t * PADW + 2 * n]     = hr;
            Hs[t * PADW + 2 * n + 1] = hi;
        }
        int b  = m0 >> 12;
        int c0 = (m0 & 4095) >> 4;
        *(float2*)&E[((size_t)(b * 64 + n) * NC + c0 + cl) * 2] = make_float2(hr, hi);
    }
    __syncthreads();

    // ---- Hs -> H_loc (bf16) ----
#pragma unroll
    for (int q = 0; q < 2; ++q) {
        int r = q * 32 + tr;
        int cb = tc * 16;
        const float* row = &Hs[r * PADW + cb];
        ushort8 o0, o1;
#pragma unroll
        for (int j = 0; j < 8; ++j) o0[j] = f2bf(row[j]);
#pragma unroll
        for (int j = 0; j < 8; ++j) o1[j] = f2bf(row[8 + j]);
        *(ushort8*)&Hloc[(size_t)(m0 + r) * N2 + cb]     = o0;
        *(ushort8*)&Hloc[(size_t)(m0 + r) * N2 + cb + 8] = o1;
    }
}

// ---------------------------------------------------------------------------
// scan_carry_par: grid (8 batches, 8 n-groups); per wave 2 chains.
// Kogge-Stone over 4 segments of 64 chunks. Writes exclusive prefix P.
// ---------------------------------------------------------------------------
__global__ __launch_bounds__(256) void scan_carry_par(
    const float* __restrict__ E, const float* __restrict__ abar,
    float* __restrict__ P)
{
    const int b    = blockIdx.x;
    const int g0   = blockIdx.y * 8;
    const int wv   = threadIdx.x >> 6;
    const int lane = threadIdx.x & 63;

    for (int n = g0 + wv * 2; n < g0 + wv * 2 + 2; ++n) {
        float2 ab = *(const float2*)&abar[2 * n];
        float ar = ab.x, ai = ab.y;
        for (int k = 0; k < 4; ++k) {     // aL = ab^16
            float t = ar * ar - ai * ai;  ai = 2.f * ar * ai;  ar = t;
        }
        float pr[7], pi[7];               // aL^(2^k)
        pr[0] = ar; pi[0] = ai;
#pragma unroll
        for (int k = 1; k < 7; ++k) {
            pr[k] = pr[k-1] * pr[k-1] - pi[k-1] * pi[k-1];
            pi[k] = 2.f * pr[k-1] * pi[k-1];
        }
        int L = lane + 1;                 // aL^(lane+1)
        float wr = 1.f, wi = 0.f;
#pragma unroll
        for (int k = 0; k < 7; ++k) if ((L >> k) & 1) {
            float t = wr * pr[k] - wi * pi[k];
            wi = wr * pi[k] + wi * pr[k]; wr = t;
        }
        const float* Eb = E + (size_t)(b * 64 + n) * NC * 2;
        float cr = 0.f, ci = 0.f;
        for (int s = 0; s < 4; ++s) {
            float2 e = *(const float2*)&Eb[(s * 64 + lane) * 2];
            float xr = e.x, xi = e.y;
#pragma unroll
            for (int k = 0; k < 6; ++k) {
                int d = 1 << k;
                float tr_ = __shfl_up(xr, (unsigned)d);
                float ti_ = __shfl_up(xi, (unsigned)d);
                if (lane >= d) {
                    xr = fmaf(pr[k], tr_, fmaf(-pi[k], ti_, xr));
                    xi = fmaf(pr[k], ti_, fmaf(pi[k], tr_, xi));
                }
            }
            float gr = fmaf(wr, cr, fmaf(-wi, ci, xr));
            float gi = fmaf(wr, ci, fmaf(wi, cr, xi));
            float exr = __shfl_up(gr, 1u);
            float exi = __shfl_up(gi, 1u);
            if (lane == 0) { exr = cr; exi = ci; }
            *(float2*)&P[(size_t)(b * NC + s * 64 + lane) * N2 + 2 * n] =
                make_float2(exr, exi);
            cr = __shfl(gr, 63);
            ci = __shfl(gi, 63);
        }
    }
}

// ---------------------------------------------------------------------------
// gemm2_fused: y[m][d] = [u | Hfix][m] . W2b[d], 128x128 tile, Ktot=640,
// double-buffered 2-phase pipeline. A1 from u_bf via global_load_lds.
// ---------------------------------------------------------------------------
template<bool A1BF>
__global__ __launch_bounds__(256) void gemm2_fused(
    const float* __restrict__ uf,
    const unsigned short* __restrict__ ubf,
    const unsigned short* __restrict__ Hloc,
    const unsigned short* __restrict__ W2b,
    const float* __restrict__ P,
    const float* __restrict__ powtab,
    float* __restrict__ y)
{
    __shared__ __align__(16) char smem[65536];
    unsigned short* As0 = (unsigned short*)smem;             // 16 KB
    unsigned short* As1 = (unsigned short*)(smem + 16384);
    unsigned short* Bs0 = (unsigned short*)(smem + 32768);
    unsigned short* Bs1 = (unsigned short*)(smem + 49152);

    const int tid  = threadIdx.x;
    const int lane = tid & 63;
    const int w    = tid >> 6;
    const int wm   = (w >> 1) * 64;
    const int wn   = (w & 1) * 64;
    const int m0   = blockIdx.x * 128;
    const int n0   = blockIdx.y * 128;
    const int tr = tid >> 3, tc = tid & 7;

    f32x4 acc[4][4];
#pragma unroll
    for (int i = 0; i < 4; ++i)
#pragma unroll
        for (int j = 0; j < 4; ++j)
            acc[i][j] = (f32x4){0.f, 0.f, 0.f, 0.f};

    auto stage = [&](int t, unsigned short* Asb, unsigned short* Bsb) {
        const int k0 = t * 64;
#pragma unroll
        for (int q = 0; q < 4; ++q) {            // B tile
            int r = q * 32 + tr;
            int cs = tc ^ (r & 7);
            gload_lds16(W2b + (size_t)(n0 + r) * 640 + k0 + cs * 8,
                        (char*)Bsb + (q * 256 + tid) * 16);
        }
        if (k0 < D_MODEL) {                      // A1: u (bf16 via DMA or f32)
            if constexpr (A1BF) {
#pragma unroll
                for (int q = 0; q < 4; ++q) {
                    int r = q * 32 + tr;
                    int cs = tc ^ (r & 7);
                    gload_lds16(ubf + (size_t)(m0 + r) * D_MODEL + k0 + cs * 8,
                                (char*)Asb + (q * 256 + tid) * 16);
                }
            } else {
#pragma unroll
                for (int q = 0; q < 4; ++q) {
                    int r = q * 32 + tr;
                    const float* src = uf + (size_t)(m0 + r) * D_MODEL + k0 + tc * 8;
                    float4 v0 = *(const float4*)src;
                    float4 v1 = *(const float4*)(src + 4);
                    ushort8 p;
                    p[0] = f2bf(v0.x); p[1] = f2bf(v0.y); p[2] = f2bf(v0.z); p[3] = f2bf(v0.w);
                    p[4] = f2bf(v1.x); p[5] = f2bf(v1.y); p[6] = f2bf(v1.z); p[7] = f2bf(v1.w);
                    int cd = tc ^ (r & 7);
                    *(ushort8*)((char*)Asb + r * 128 + cd * 16) = p;
                }
            }
        } else {                                 // A2: Hfix = Hloc + a^(i+1)*P
            const int kk0 = k0 - D_MODEL;
#pragma unroll
            for (int q = 0; q < 4; ++q) {
                int r = q * 32 + tr;
                int m = m0 + r;
                int b = m >> 12, tt = m & 4095;
                int c = tt >> 4, i = tt & 15;
                ushort8 hl = *(const ushort8*)&Hloc[(size_t)m * N2 + kk0 + tc * 8];
                const float* Pp = P + (size_t)(b * NC + c) * N2 + kk0 + tc * 8;
                float4 p0 = *(const float4*)Pp;
                float4 p1 = *(const float4*)(Pp + 4);
                const float* Wp = powtab + i * 128 + kk0 + tc * 8;
                float4 w0 = *(const float4*)Wp;
                float4 w1 = *(const float4*)(Wp + 4);
                ushort8 p;
                p[0] = f2bf(fmaf(w0.x, p0.x, fmaf(-w0.y, p0.y, bf2f(hl[0]))));
                p[1] = f2bf(fmaf(w0.x, p0.y, fmaf( w0.y, p0.x, bf2f(hl[1]))));
                p[2] = f2bf(fmaf(w0.z, p0.z, fmaf(-w0.w, p0.w, bf2f(hl[2]))));
                p[3] = f2bf(fmaf(w0.z, p0.w, fmaf( w0.w, p0.z, bf2f(hl[3]))));
                p[4] = f2bf(fmaf(w1.x, p1.x, fmaf(-w1.y, p1.y, bf2f(hl[4]))));
                p[5] = f2bf(fmaf(w1.x, p1.y, fmaf( w1.y, p1.x, bf2f(hl[5]))));
                p[6] = f2bf(fmaf(w1.z, p1.z, fmaf(-w1.w, p1.w, bf2f(hl[6]))));
                p[7] = f2bf(fmaf(w1.z, p1.w, fmaf( w1.w, p1.z, bf2f(hl[7]))));
                int cd = tc ^ (r & 7);
                *(ushort8*)((char*)Asb + r * 128 + cd * 16) = p;
            }
        }
    };
    auto compute = [&](const unsigned short* Asb, const unsigned short* Bsb) {
#pragma unroll
        for (int kk = 0; kk < 2; ++kk) {
            bf16x8 a[4], b[4];
#pragma unroll
            for (int i = 0; i < 4; ++i) {
                int row = wm + i * 16 + (lane & 15);
                int kb  = kk * 64 + ((lane >> 4) << 4);
                a[i] = *(const bf16x8*)((const char*)Asb + row * 128 + (kb ^ ((row & 7) << 4)));
            }
#pragma unroll
            for (int j = 0; j < 4; ++j) {
                int row = wn + j * 16 + (lane & 15);
                int kb  = kk * 64 + ((lane >> 4) << 4);
                b[j] = *(const bf16x8*)((const char*)Bsb + row * 128 + (kb ^ ((row & 7) << 4)));
            }
#pragma unroll
            for (int i = 0; i < 4; ++i)
#pragma unroll
                for (int j = 0; j < 4; ++j)
                    acc[i][j] = __builtin_amdgcn_mfma_f32_16x16x32_bf16(a[i], b[j], acc[i][j], 0, 0, 0);
        }
    };

    unsigned short *Ac = As0, *Bc = Bs0, *An = As1, *Bn = Bs1;
    stage(0, Ac, Bc);
    for (int t = 0; t < 10; ++t) {
        __syncthreads();                 // staged(t) ready; compute(t-1) done
        if (t + 1 < 10) stage(t + 1, An, Bn);
        compute(Ac, Bc);
        unsigned short* s;
        s = Ac; Ac = An; An = s;
        s = Bc; Bc = Bn; Bn = s;
    }

#pragma unroll
    for (int i = 0; i < 4; ++i)
#pragma unroll
        for (int j = 0; j < 4; ++j) {
            int col = n0 + wn + j * 16 + (lane & 15);
#pragma unroll
            for (int r = 0; r < 4; ++r) {
                int row = m0 + wm + i * 16 + ((lane >> 4) << 2) + r;
                y[(size_t)row * D_MODEL + col] = acc[i][j][r];
            }
        }
}

// ---------------------------------------------------------------------------
extern "C" void kernel_launch(void* const* d_in, const int* in_sizes, int n_in,
                              void* d_out, int out_size, void* d_ws, size_t ws_size,
                              hipStream_t stream)
{
    const float* u   = (const float*)d_in[0];
    const float* lar = (const float*)d_in[1];
    const float* lai = (const float*)d_in[2];
    const float* Bw  = (const float*)d_in[3];
    const float* Cw  = (const float*)d_in[4];
    const float* Dw  = (const float*)d_in[5];
    float* y = (float*)d_out;
    char* ws = (char*)d_ws;

    float*          abar   = (float*)(ws + OFFB_ABAR);
    float*          powtab = (float*)(ws + OFFB_POWTAB);
    unsigned short* Bwpb   = (unsigned short*)(ws + OFFB_BWPB);
    unsigned short* W2b    = (unsigned short*)(ws + OFFB_W2B);
    float*          E      = (float*)(ws + OFFB_E);
    float*          P      = (float*)(ws + OFFB_P);
    unsigned short* Hloc   = (unsigned short*)(ws + OFFB_HLOC);
    unsigned short* u_bf   = (unsigned short*)(ws + OFFB_UBF);

    const int use_ubf = (ws_size >= (size_t)WS_NEED_UBF) ? 1 : 0;

    hipLaunchKernelGGL(prep_kernel, dim3(128), dim3(256), 0, stream,
                       lar, lai, Bw, Cw, Dw, abar, powtab, Bwpb, W2b);
    hipLaunchKernelGGL(gemm1_fused, dim3(MTOT / 64), dim3(256), 0, stream,
                       u, Bwpb, abar, Hloc, E, u_bf, use_ubf);
    hipLaunchKernelGGL(scan_carry_par, dim3(8, 8), dim3(256), 0, stream,
                       E, abar, P);
    if (use_ubf) {
        hipLaunchKernelGGL((gemm2_fused<true>), dim3(MTOT / 128, D_MODEL / 128),
                           dim3(256), 0, stream,
                           u, u_bf, Hloc, W2b, P, powtab, y);
    } else {
        hipLaunchKernelGGL((gemm2_fused<false>), dim3(MTOT / 128, D_MODEL / 128),
                           dim3(256), 0, stream,
                           u, u_bf, Hloc, W2b, P, powtab, y);
    }
}